// Round 6
// baseline (146.260 us; speedup 1.0000x reference)
//
#include <hip/hip_runtime.h>

#define TLEN   500000
#define NITER  100
#define DHALF  10                 // band half-width; weights ~0.135*(1.1)^d/d!
#define NOFF   (2*DHALF+1)        // 21 offsets
#define STRIP  20                 // edge strip width
#define EWIN   64                 // edge window (one wave)
#define CT     256                // conv threads
#define CCPT   2                  // conv cols per thread
#define CCOLS  (CT*CCPT)          // 512
#define CWIN   (CCOLS + 2*DHALF)  // 532
#define NCONV  ((TLEN - 2*STRIP + CCOLS - 1) / CCOLS)   // 977

// Opacity pin: forces a value into a VGPR and makes it non-rematerializable,
// so the compiler cannot fold it back into per-iteration LDS reads.
#define PIN(x) asm volatile("" : "+v"(x))

// ============ K1: band weights (blocks 0-5) + edge strips (blocks 6,7) ============
// One wave per block. Every block builds the 224 operator coefficients
// (double-precision Gauss-Jordan in LDS, redundant per block), hoists the 184
// hot-loop coefficients into PINNED VGPRs, then runs the 100-iteration loop as
// pure VALU FMA + 16 bpermutes with zero memory traffic.
__global__ __launch_bounds__(64, 1) void band_and_edges(
    const float* __restrict__ xs, const float* __restrict__ ys,
    const float* __restrict__ F, const float* __restrict__ H,
    const float* __restrict__ Q, const float* __restrict__ R,
    const float* __restrict__ gam,
    float* __restrict__ wout,            // d_ws: 21*12*8 floats
    float* __restrict__ out)
{
  __shared__ double dQaug[8][16];
  __shared__ double dRaug[4][8];
  __shared__ double dFtQi[64], dHtRi[32], dA1[64], dB2[64];
  __shared__ float fmats[224];

  const int lane = threadIdx.x;
  const int b    = blockIdx.x;
  const int r8 = lane >> 3, c8 = lane & 7;

  // ---- augmented systems ----
  dQaug[r8][c8]     = (double)Q[r8*8 + c8];
  dQaug[r8][c8 + 8] = (c8 == r8) ? 1.0 : 0.0;
  if (lane < 32) {
    int rr = lane >> 3, cr = lane & 7;
    dRaug[rr][cr] = (cr < 4) ? (double)R[rr*4 + cr] : ((cr - 4 == rr) ? 1.0 : 0.0);
  }
  __syncthreads();
  // ---- Gauss-Jordan (no pivoting: Q,R SPD) ----
  for (int col = 0; col < 8; ++col) {
    double piv = dQaug[col][col];
    double fq  = dQaug[r8][col];
    double p1  = dQaug[col][c8], p2 = dQaug[col][c8 + 8];
    double m1  = dQaug[r8][c8],  m2 = dQaug[r8][c8 + 8];
    double rpiv = 1.0, frr = 0.0, pr = 0.0, mr = 0.0;
    const bool doR = (lane < 32) && (col < 4);
    if (doR) {
      int rr = lane >> 3, cr = lane & 7;
      rpiv = dRaug[col][col]; frr = dRaug[rr][col];
      pr = dRaug[col][cr];    mr = dRaug[rr][cr];
    }
    __syncthreads();
    dQaug[r8][c8]     = (r8 == col) ? m1 / piv : m1 - fq * (p1 / piv);
    dQaug[r8][c8 + 8] = (r8 == col) ? m2 / piv : m2 - fq * (p2 / piv);
    if (doR) {
      int rr = lane >> 3, cr = lane & 7;
      dRaug[rr][cr] = (rr == col) ? mr / rpiv : mr - frr * (pr / rpiv);
    }
    __syncthreads();
  }
  // ---- operator products ----
  {
    double s = 0.0;
    #pragma unroll
    for (int k = 0; k < 8; ++k) s += (double)F[k*8 + r8] * dQaug[k][c8 + 8];
    dFtQi[r8*8 + c8] = s;
  }
  if (lane < 32) {
    int i = lane >> 2, j = lane & 3;
    double s = 0.0;
    #pragma unroll
    for (int k = 0; k < 4; ++k) s += (double)H[k*8 + i] * dRaug[k][j + 4];
    dHtRi[i*4 + j] = s;
  }
  dA1[r8*8 + c8] = (c8 == 0) ? 0.0 : -dQaug[r8][c8 + 8];
  __syncthreads();
  dB2[r8*8 + c8] = (c8 == 7) ? 0.0 : dFtQi[r8*8 + c8];
  __syncthreads();
  {
    const double g = (double)gam[0];
    double sp = 0.0;
    #pragma unroll
    for (int k = 0; k < 8; ++k) sp -= dA1[r8*8 + k] * (double)F[k*8 + c8];
    double t = dA1[r8*8 + c8];
    #pragma unroll
    for (int k = 0; k < 8; ++k) t -= dB2[r8*8 + k] * (double)F[k*8 + c8];
    #pragma unroll
    for (int k = 0; k < 4; ++k) t -= dHtRi[r8*4 + k] * (double)H[k*8 + c8];
    // lane (i=r8, k=c8) owns Mx/Mp[i][k] -> transposed slots [k*8+i]
    fmats[       c8*8 + r8] = (float)(((r8 == c8) ? 1.0 : 0.0) + g * t);
    fmats[ 64 +  c8*8 + r8] = (float)(g * sp);
    fmats[128 +  c8*8 + r8] = (float)(g * dB2[r8*8 + c8]);
    if (lane < 32) {
      int i = lane >> 2, j = lane & 3;   // owns HtRi[i][j]
      fmats[192 + j*8 + i] = (float)(g * dHtRi[i*4 + j]);
    }
  }
  __syncthreads();

  // ---- hoist coefficients into VGPRs and PIN them ----
  float cmv[64], pmv[64], fuv[56];
  #pragma unroll
  for (int t = 0; t < 64; ++t) { cmv[t] = fmats[t];       PIN(cmv[t]); }
  #pragma unroll
  for (int t = 0; t < 64; ++t) { pmv[t] = fmats[64 + t];  PIN(pmv[t]); }
  #pragma unroll
  for (int t = 0; t < 56; ++t) { fuv[t] = fmats[128 + t]; PIN(fuv[t]); }

  if (b < 6) {
    // ---- weight recurrence: W'_s = Cm*W_s + P*W_{s+1} + Fu*W_{s-1} ----
    const int sub = lane / 23;
    const int s   = lane % 23;          // slot; 0 and 22 are guards
    const int c   = 2*b + sub;          // source column 0..11
    const bool act   = (sub < 2);
    const bool guard = (s == 0) || (s == 22) || !act;
    float x[8];
    #pragma unroll
    for (int r = 0; r < 8; ++r) x[r] = 0.0f;
    if (act && c < 8 && s == DHALF + 1) x[c] = 1.0f;   // W_0 = I
    float seed[8];
    {
      const int gk = (c >= 8 && c < 12) ? (c - 8) : 0;
      const bool inj = act && (c >= 8) && (c < 12) && (s == DHALF + 1);
      #pragma unroll
      for (int i = 0; i < 8; ++i) { seed[i] = inj ? fmats[192 + gk*8 + i] : 0.0f; PIN(seed[i]); }
    }
    const int sl = (lane == 0)  ? 0  : lane - 1;
    const int sr = (lane >= 63) ? 63 : lane + 1;
    #pragma unroll 1
    for (int it = 0; it < NITER; ++it) {
      float xl[8], xr[8];
      #pragma unroll
      for (int r = 0; r < 8; ++r) { xl[r] = __shfl(x[r], sl); xr[r] = __shfl(x[r], sr); }
      float nx[8];
      #pragma unroll
      for (int i = 0; i < 8; ++i) nx[i] = seed[i];
      #pragma unroll
      for (int k = 0; k < 8; ++k) {
        #pragma unroll
        for (int i = 0; i < 8; ++i) {
          nx[i] = fmaf(cmv[k*8 + i], x[k],  nx[i]);      // Cm
          nx[i] = fmaf(pmv[k*8 + i], xr[k], nx[i]);      // P  * W_{s+1}
          if (k < 7)
            nx[i] = fmaf(fuv[k*8 + i], xl[k], nx[i]);    // Fu * W_{s-1}
        }
      }
      #pragma unroll
      for (int r = 0; r < 8; ++r) x[r] = guard ? 0.0f : nx[r];
    }
    if (act && s >= 1 && s <= 21) {
      #pragma unroll
      for (int i = 0; i < 8; ++i) wout[((s - 1)*12 + c)*8 + i] = x[i];
    }
    return;
  }

  // ---- edge strips: exact iteration on 64 columns, halo via shuffles ----
  const bool left = (b == 6);
  const int col = left ? lane : (TLEN - EWIN + lane);
  float x[8], gy[8];
  #pragma unroll
  for (int r = 0; r < 8; ++r) x[r] = xs[r*TLEN + col];
  {
    float yv[4];
    #pragma unroll
    for (int r = 0; r < 4; ++r) yv[r] = ys[r*TLEN + col];
    #pragma unroll
    for (int i = 0; i < 8; ++i) {
      float a =      fmats[192 +      i] * yv[0];
      a = fmaf(fmats[192 +  8 + i], yv[1], a);
      a = fmaf(fmats[192 + 16 + i], yv[2], a);
      a = fmaf(fmats[192 + 24 + i], yv[3], a);
      gy[i] = a;
      PIN(gy[i]);
    }
  }
  const int sl = (lane > 0)  ? lane - 1 : 0;    // clamp: col 0 replicates (x_past)
  const int sr = (lane < 63) ? lane + 1 : 63;   // clamp: col T-1 replicates (x_fut)
  #pragma unroll 1
  for (int it = 0; it < NITER; ++it) {
    float xl[8], xr[8];
    #pragma unroll
    for (int r = 0; r < 8; ++r) { xl[r] = __shfl(x[r], sl); xr[r] = __shfl(x[r], sr); }
    float nx[8];
    #pragma unroll
    for (int i = 0; i < 8; ++i) nx[i] = gy[i];
    #pragma unroll
    for (int k = 0; k < 8; ++k) {
      #pragma unroll
      for (int i = 0; i < 8; ++i) {
        nx[i] = fmaf(cmv[k*8 + i], x[k],  nx[i]);        // Cm
        nx[i] = fmaf(pmv[k*8 + i], xl[k], nx[i]);        // P  * x_{t-1}
        if (k < 7)
          nx[i] = fmaf(fuv[k*8 + i], xr[k], nx[i]);      // Fu * x_{t+1}
      }
    }
    #pragma unroll
    for (int r = 0; r < 8; ++r) x[r] = nx[r];
  }
  if (left) {
    if (lane < STRIP)
      #pragma unroll
      for (int r = 0; r < 8; ++r) out[r*TLEN + col] = x[r];
  } else {
    if (lane >= EWIN - STRIP)
      #pragma unroll
      for (int r = 0; r < 8; ++r) out[r*TLEN + col] = x[r];
  }
}

// ============ K2: interior band convolution ============
__global__ __launch_bounds__(CT) void kgm_conv(
    const float* __restrict__ xs, const float* __restrict__ ys,
    const float* __restrict__ wq, float* __restrict__ out)
{
  __shared__ __align__(16) float buf[CWIN * 12];   // [col][12], 48B stride
  const int tid = threadIdx.x;
  const int c0  = STRIP + blockIdx.x * CCOLS;
  for (int k = 0; k < 12; ++k) {
    const float* src = (k < 8) ? (xs + k*TLEN) : (ys + (k-8)*TLEN);
    for (int c = tid; c < CWIN; c += CT) {
      int g = c0 - DHALF + c;
      if (g > TLEN - 1) g = TLEN - 1;
      buf[c*12 + k] = src[g];
    }
  }
  __syncthreads();

  const float* base = buf + (2*tid)*12;
  float a0[8] = {0,0,0,0,0,0,0,0};
  float a1[8] = {0,0,0,0,0,0,0,0};
  float A[12], B[12];
  {
    float4 u = *(const float4*)(base);
    float4 v = *(const float4*)(base + 4);
    float4 w = *(const float4*)(base + 8);
    A[0]=u.x;A[1]=u.y;A[2]=u.z;A[3]=u.w;A[4]=v.x;A[5]=v.y;A[6]=v.z;A[7]=v.w;A[8]=w.x;A[9]=w.y;A[10]=w.z;A[11]=w.w;
  }
  #define LOADCOL(dst, j1) { \
    const float* p_ = base + (j1)*12; \
    float4 u = *(const float4*)(p_); \
    float4 v = *(const float4*)(p_ + 4); \
    float4 w = *(const float4*)(p_ + 8); \
    dst[0]=u.x;dst[1]=u.y;dst[2]=u.z;dst[3]=u.w;dst[4]=v.x;dst[5]=v.y;dst[6]=v.z;dst[7]=v.w;dst[8]=w.x;dst[9]=w.y;dst[10]=w.z;dst[11]=w.w; }
  #define FMABLK(wd, c0v, c1v) { \
    _Pragma("unroll") \
    for (int k = 0; k < 12; ++k) { \
      _Pragma("unroll") \
      for (int i = 0; i < 8; ++i) { \
        float wk = (wd)[k*8 + i]; \
        a0[i] = fmaf(wk, (c0v)[k], a0[i]); \
        a1[i] = fmaf(wk, (c1v)[k], a1[i]); \
      } } }

  #pragma unroll 1
  for (int j = 0; j + 2 <= NOFF; j += 2) {
    LOADCOL(B, j + 1);
    FMABLK(wq + j*96, A, B);
    LOADCOL(A, j + 2);
    FMABLK(wq + (j+1)*96, B, A);
  }
  LOADCOL(B, NOFF);
  FMABLK(wq + (NOFF-1)*96, A, B);
  #undef LOADCOL
  #undef FMABLK

  const int col = c0 + 2*tid;
  if (col < TLEN - STRIP) {
    #pragma unroll
    for (int i = 0; i < 8; ++i) out[i*TLEN + col] = a0[i];
  }
  if (col + 1 < TLEN - STRIP) {
    #pragma unroll
    for (int i = 0; i < 8; ++i) out[i*TLEN + col + 1] = a1[i];
  }
}

extern "C" void kernel_launch(void* const* d_in, const int* in_sizes, int n_in,
                              void* d_out, int out_size, void* d_ws, size_t ws_size,
                              hipStream_t stream)
{
  (void)in_sizes; (void)n_in; (void)out_size; (void)ws_size;
  const float* xs = (const float*)d_in[0];
  const float* ys = (const float*)d_in[1];
  const float* F  = (const float*)d_in[2];
  const float* H  = (const float*)d_in[3];
  const float* Q  = (const float*)d_in[4];
  const float* R  = (const float*)d_in[5];
  const float* ga = (const float*)d_in[6];
  float* ws  = (float*)d_ws;     // [0, 2016): band weights
  float* out = (float*)d_out;
  band_and_edges<<<8, 64, 0, stream>>>(xs, ys, F, H, Q, R, ga, ws, out);
  kgm_conv<<<NCONV, CT, 0, stream>>>(xs, ys, ws, out);
}

// Round 7
// 58.494 us; speedup vs baseline: 2.5004x; 2.5004x over previous
//
#include <hip/hip_runtime.h>

#define TLEN   500000
#define NITER  100
#define DHALF  10                 // band half-width; weights ~0.135*(1.1)^d/d!
#define NOFF   (2*DHALF+1)        // 21 offsets
#define STRIP  20                 // edge strip width
#define EWIN   32                 // edge window (32 cols x 8 rows = 256 lanes)
#define CT     256                // conv threads
#define CCPT   2                  // conv cols per thread
#define CCOLS  (CT*CCPT)          // 512
#define CWIN   (CCOLS + 2*DHALF)  // 532
#define NCONV  ((TLEN - 2*STRIP + CCOLS - 1) / CCOLS)   // 977

// ============ K1: band weights (blocks 0-11) + edge strips (blocks 12,13) ============
// Fine-grained mapping: one lane per (column-state, output-row i). Each lane keeps
// only row i of Cm/P/Fu (23 coefficients) in registers; column states live in a
// ping-ponged LDS buffer with ONE barrier per iteration.
__global__ __launch_bounds__(256) void band_and_edges(
    const float* __restrict__ xs, const float* __restrict__ ys,
    const float* __restrict__ F, const float* __restrict__ H,
    const float* __restrict__ Q, const float* __restrict__ R,
    const float* __restrict__ gam,
    float* __restrict__ wout,            // d_ws: 21*12*8 floats
    float* __restrict__ out)
{
  __shared__ double dQaug[8][16];
  __shared__ double dRaug[4][8];
  __shared__ double dFtQi[64], dHtRi[32], dA1[64], dB2[64];
  __shared__ float fmats[224];
  __shared__ __align__(16) float st[2][34][8];   // ping-pong column states

  const int tid = threadIdx.x;
  const int b   = blockIdx.x;
  const int r8  = (tid >> 3) & 7;
  const int c8  = tid & 7;

  // ---------- double-precision operator construction (redundant per block) ----------
  if (tid < 64) {
    dQaug[r8][c8]     = (double)Q[r8*8 + c8];
    dQaug[r8][c8 + 8] = (c8 == r8) ? 1.0 : 0.0;
  } else if (tid < 96) {
    int t = tid - 64, rr = t >> 3, cr = t & 7;
    dRaug[rr][cr] = (cr < 4) ? (double)R[rr*4 + cr] : ((cr - 4 == rr) ? 1.0 : 0.0);
  }
  __syncthreads();
  for (int col = 0; col < 8; ++col) {      // Gauss-Jordan (Q,R SPD: no pivoting)
    double piv = 1, fq = 0, p1 = 0, p2 = 0, m1 = 0, m2 = 0;
    double rpiv = 1, frr = 0, pr = 0, mr = 0;
    const bool doQ = tid < 64;
    const bool doR = (tid >= 64 && tid < 96 && col < 4);
    if (doQ) {
      piv = dQaug[col][col]; fq = dQaug[r8][col];
      p1 = dQaug[col][c8];   p2 = dQaug[col][c8 + 8];
      m1 = dQaug[r8][c8];    m2 = dQaug[r8][c8 + 8];
    }
    if (doR) {
      int t = tid - 64, rr = t >> 3, cr = t & 7;
      rpiv = dRaug[col][col]; frr = dRaug[rr][col];
      pr = dRaug[col][cr];    mr = dRaug[rr][cr];
    }
    __syncthreads();
    if (doQ) {
      dQaug[r8][c8]     = (r8 == col) ? m1 / piv : m1 - fq * (p1 / piv);
      dQaug[r8][c8 + 8] = (r8 == col) ? m2 / piv : m2 - fq * (p2 / piv);
    }
    if (doR) {
      int t = tid - 64, rr = t >> 3, cr = t & 7;
      dRaug[rr][cr] = (rr == col) ? mr / rpiv : mr - frr * (pr / rpiv);
    }
    __syncthreads();
  }
  if (tid < 64) {
    double s = 0.0;
    #pragma unroll
    for (int k = 0; k < 8; ++k) s += (double)F[k*8 + r8] * dQaug[k][c8 + 8];
    dFtQi[r8*8 + c8] = s;
    dA1[r8*8 + c8] = (c8 == 0) ? 0.0 : -dQaug[r8][c8 + 8];
  } else if (tid < 96) {
    int t = tid - 64, i = t >> 2, j = t & 3;
    double s = 0.0;
    #pragma unroll
    for (int k = 0; k < 4; ++k) s += (double)H[k*8 + i] * dRaug[k][j + 4];
    dHtRi[i*4 + j] = s;
  }
  __syncthreads();
  if (tid < 64) dB2[r8*8 + c8] = (c8 == 7) ? 0.0 : dFtQi[r8*8 + c8];
  __syncthreads();
  {
    const double g = (double)gam[0];
    if (tid < 64) {
      double sp = 0.0;
      #pragma unroll
      for (int k = 0; k < 8; ++k) sp -= dA1[r8*8 + k] * (double)F[k*8 + c8];
      double t2 = dA1[r8*8 + c8];
      #pragma unroll
      for (int k = 0; k < 8; ++k) t2 -= dB2[r8*8 + k] * (double)F[k*8 + c8];
      #pragma unroll
      for (int k = 0; k < 4; ++k) t2 -= dHtRi[r8*4 + k] * (double)H[k*8 + c8];
      // lane (i=r8, k=c8) owns element [i][k] -> transposed slot [k*8+i]
      fmats[       c8*8 + r8] = (float)(((r8 == c8) ? 1.0 : 0.0) + g * t2);
      fmats[ 64 +  c8*8 + r8] = (float)(g * sp);
      fmats[128 +  c8*8 + r8] = (float)(g * dB2[r8*8 + c8]);
    } else if (tid < 96) {
      int t = tid - 64, i = t >> 2, j = t & 3;
      fmats[192 + j*8 + i] = (float)(g * dHtRi[i*4 + j]);
    }
  }
  __syncthreads();

  // ---------- per-lane coefficient rows (23 registers) ----------
  const int i = tid & 7;       // output row owned by this lane
  const int g = tid >> 3;      // group: slot (band) or column (edge)
  float cmr[8], pmr[8], fur[7];
  #pragma unroll
  for (int k = 0; k < 8; ++k) {
    cmr[k] = fmats[       k*8 + i];
    pmr[k] = fmats[ 64 +  k*8 + i];
    if (k < 7) fur[k] = fmats[128 + k*8 + i];
  }
  float* const stf = (float*)st;
  const int BUF = 34*8;

  if (b < 12) {
    // ---- band recurrence: W'_s = Cm*W_s + P*W_{s+1} + Fu*W_{s-1}, guards at s=0,22 ----
    const int c = b;                    // source column 0..11 (8..11 = y columns)
    const bool act = tid < 168;         // 21 slots x 8 rows
    const int s = g + 1;                // slot 1..21
    for (int idx = tid; idx < 2*BUF; idx += 256) stf[idx] = 0.0f;
    __syncthreads();
    if (act && c < 8 && s == DHALF + 1 && i == c) st[0][s][i] = 1.0f;   // W_0 = I
    const float seed = (act && c >= 8 && s == DHALF + 1) ? fmats[192 + (c - 8)*8 + i] : 0.0f;
    __syncthreads();
    int p = 0;
    float last = 0.0f;
    #pragma unroll 1
    for (int it = 0; it < NITER; ++it) {
      if (act) {
        const float* sp_ = stf + p*BUF;
        const float4 o0 = *(const float4*)(sp_ + s*8);
        const float4 o1 = *(const float4*)(sp_ + s*8 + 4);
        const float4 u0 = *(const float4*)(sp_ + (s + 1)*8);
        const float4 u1 = *(const float4*)(sp_ + (s + 1)*8 + 4);
        const float4 d0 = *(const float4*)(sp_ + (s - 1)*8);
        const float4 d1 = *(const float4*)(sp_ + (s - 1)*8 + 4);
        float a0 = seed, a1 = 0.0f, a2 = 0.0f;
        a0 = fmaf(cmr[0], o0.x, a0); a0 = fmaf(cmr[1], o0.y, a0);
        a0 = fmaf(cmr[2], o0.z, a0); a0 = fmaf(cmr[3], o0.w, a0);
        a0 = fmaf(cmr[4], o1.x, a0); a0 = fmaf(cmr[5], o1.y, a0);
        a0 = fmaf(cmr[6], o1.z, a0); a0 = fmaf(cmr[7], o1.w, a0);
        a1 = fmaf(pmr[0], u0.x, a1); a1 = fmaf(pmr[1], u0.y, a1);
        a1 = fmaf(pmr[2], u0.z, a1); a1 = fmaf(pmr[3], u0.w, a1);
        a1 = fmaf(pmr[4], u1.x, a1); a1 = fmaf(pmr[5], u1.y, a1);
        a1 = fmaf(pmr[6], u1.z, a1); a1 = fmaf(pmr[7], u1.w, a1);
        a2 = fmaf(fur[0], d0.x, a2); a2 = fmaf(fur[1], d0.y, a2);
        a2 = fmaf(fur[2], d0.z, a2); a2 = fmaf(fur[3], d0.w, a2);
        a2 = fmaf(fur[4], d1.x, a2); a2 = fmaf(fur[5], d1.y, a2);
        a2 = fmaf(fur[6], d1.z, a2);
        last = a0 + a1 + a2;
        stf[(p^1)*BUF + s*8 + i] = last;
      }
      __syncthreads();
      p ^= 1;
    }
    if (act) wout[((s - 1)*12 + c)*8 + i] = last;
    return;
  }

  // ---- edge strips: 32 columns x 8 rows, true clamp at the outer boundary ----
  const bool left = (b == 12);
  const int col  = g;                                    // 0..31
  const int gcol = left ? col : (TLEN - EWIN + col);
  const int sL = (col > 0) ? col - 1 : 0;                // replicate at window edge
  const int sR = (col < EWIN - 1) ? col + 1 : EWIN - 1;
  const float xv = xs[i*TLEN + gcol];
  float gyv;
  {
    gyv = fmats[192 +      i] * ys[0*TLEN + gcol];
    gyv = fmaf(fmats[192 +  8 + i], ys[1*TLEN + gcol], gyv);
    gyv = fmaf(fmats[192 + 16 + i], ys[2*TLEN + gcol], gyv);
    gyv = fmaf(fmats[192 + 24 + i], ys[3*TLEN + gcol], gyv);
  }
  st[0][col][i] = xv;
  __syncthreads();
  int p = 0;
  float last = xv;
  #pragma unroll 1
  for (int it = 0; it < NITER; ++it) {
    const float* sp_ = stf + p*BUF;
    const float4 o0 = *(const float4*)(sp_ + col*8);
    const float4 o1 = *(const float4*)(sp_ + col*8 + 4);
    const float4 l0 = *(const float4*)(sp_ + sL*8);      // x_{t-1}
    const float4 l1 = *(const float4*)(sp_ + sL*8 + 4);
    const float4 q0 = *(const float4*)(sp_ + sR*8);      // x_{t+1}
    const float4 q1 = *(const float4*)(sp_ + sR*8 + 4);
    float a0 = gyv, a1 = 0.0f, a2 = 0.0f;
    a0 = fmaf(cmr[0], o0.x, a0); a0 = fmaf(cmr[1], o0.y, a0);
    a0 = fmaf(cmr[2], o0.z, a0); a0 = fmaf(cmr[3], o0.w, a0);
    a0 = fmaf(cmr[4], o1.x, a0); a0 = fmaf(cmr[5], o1.y, a0);
    a0 = fmaf(cmr[6], o1.z, a0); a0 = fmaf(cmr[7], o1.w, a0);
    a1 = fmaf(pmr[0], l0.x, a1); a1 = fmaf(pmr[1], l0.y, a1);
    a1 = fmaf(pmr[2], l0.z, a1); a1 = fmaf(pmr[3], l0.w, a1);
    a1 = fmaf(pmr[4], l1.x, a1); a1 = fmaf(pmr[5], l1.y, a1);
    a1 = fmaf(pmr[6], l1.z, a1); a1 = fmaf(pmr[7], l1.w, a1);
    a2 = fmaf(fur[0], q0.x, a2); a2 = fmaf(fur[1], q0.y, a2);
    a2 = fmaf(fur[2], q0.z, a2); a2 = fmaf(fur[3], q0.w, a2);
    a2 = fmaf(fur[4], q1.x, a2); a2 = fmaf(fur[5], q1.y, a2);
    a2 = fmaf(fur[6], q1.z, a2);
    last = a0 + a1 + a2;
    stf[(p^1)*BUF + col*8 + i] = last;
    __syncthreads();
    p ^= 1;
  }
  if (left ? (col < STRIP) : (col >= EWIN - STRIP)) out[i*TLEN + gcol] = last;
}

// ============ K2: interior band convolution ============
__global__ __launch_bounds__(CT) void kgm_conv(
    const float* __restrict__ xs, const float* __restrict__ ys,
    const float* __restrict__ wq, float* __restrict__ out)
{
  __shared__ __align__(16) float buf[CWIN * 12];   // [col][12], 48B stride
  const int tid = threadIdx.x;
  const int c0  = STRIP + blockIdx.x * CCOLS;
  for (int k = 0; k < 12; ++k) {
    const float* src = (k < 8) ? (xs + k*TLEN) : (ys + (k-8)*TLEN);
    for (int c = tid; c < CWIN; c += CT) {
      int g = c0 - DHALF + c;
      if (g > TLEN - 1) g = TLEN - 1;
      buf[c*12 + k] = src[g];
    }
  }
  __syncthreads();

  const float* base = buf + (2*tid)*12;
  float a0[8] = {0,0,0,0,0,0,0,0};
  float a1[8] = {0,0,0,0,0,0,0,0};
  float A[12], B[12];
  {
    float4 u = *(const float4*)(base);
    float4 v = *(const float4*)(base + 4);
    float4 w = *(const float4*)(base + 8);
    A[0]=u.x;A[1]=u.y;A[2]=u.z;A[3]=u.w;A[4]=v.x;A[5]=v.y;A[6]=v.z;A[7]=v.w;A[8]=w.x;A[9]=w.y;A[10]=w.z;A[11]=w.w;
  }
  #define LOADCOL(dst, j1) { \
    const float* p_ = base + (j1)*12; \
    float4 u = *(const float4*)(p_); \
    float4 v = *(const float4*)(p_ + 4); \
    float4 w = *(const float4*)(p_ + 8); \
    dst[0]=u.x;dst[1]=u.y;dst[2]=u.z;dst[3]=u.w;dst[4]=v.x;dst[5]=v.y;dst[6]=v.z;dst[7]=v.w;dst[8]=w.x;dst[9]=w.y;dst[10]=w.z;dst[11]=w.w; }
  #define FMABLK(wd, c0v, c1v) { \
    _Pragma("unroll") \
    for (int k = 0; k < 12; ++k) { \
      _Pragma("unroll") \
      for (int ii = 0; ii < 8; ++ii) { \
        float wk = (wd)[k*8 + ii]; \
        a0[ii] = fmaf(wk, (c0v)[k], a0[ii]); \
        a1[ii] = fmaf(wk, (c1v)[k], a1[ii]); \
      } } }

  #pragma unroll 1
  for (int j = 0; j + 2 <= NOFF; j += 2) {
    LOADCOL(B, j + 1);
    FMABLK(wq + j*96, A, B);
    LOADCOL(A, j + 2);
    FMABLK(wq + (j+1)*96, B, A);
  }
  LOADCOL(B, NOFF);
  FMABLK(wq + (NOFF-1)*96, A, B);
  #undef LOADCOL
  #undef FMABLK

  const int col = c0 + 2*tid;
  if (col < TLEN - STRIP) {
    #pragma unroll
    for (int ii = 0; ii < 8; ++ii) out[ii*TLEN + col] = a0[ii];
  }
  if (col + 1 < TLEN - STRIP) {
    #pragma unroll
    for (int ii = 0; ii < 8; ++ii) out[ii*TLEN + col + 1] = a1[ii];
  }
}

extern "C" void kernel_launch(void* const* d_in, const int* in_sizes, int n_in,
                              void* d_out, int out_size, void* d_ws, size_t ws_size,
                              hipStream_t stream)
{
  (void)in_sizes; (void)n_in; (void)out_size; (void)ws_size;
  const float* xs = (const float*)d_in[0];
  const float* ys = (const float*)d_in[1];
  const float* F  = (const float*)d_in[2];
  const float* H  = (const float*)d_in[3];
  const float* Q  = (const float*)d_in[4];
  const float* R  = (const float*)d_in[5];
  const float* ga = (const float*)d_in[6];
  float* ws  = (float*)d_ws;     // [0, 2016): band weights
  float* out = (float*)d_out;
  band_and_edges<<<14, 256, 0, stream>>>(xs, ys, F, H, Q, R, ga, ws, out);
  kgm_conv<<<NCONV, CT, 0, stream>>>(xs, ys, ws, out);
}